// Round 4
// baseline (1593.249 us; speedup 1.0000x reference)
//
#include <hip/hip_runtime.h>
#include <math.h>

// SDNConv: N nodes, K=8 factors, DK=16. ROW = 128 floats/node.
// R4: identical pull to R3. CSR build de-contended: cursor arrays C/O are
// padded to one counter per 64B cache line (stride S ints, S chosen to fit
// ws_size), so the memory-side atomic unit serializes ~16 ops/line instead
// of ~256. Theory: count/fill were line-RMW-serialization bound.
// Lists: 0 = Ep dst=a nb=b (W rows 0-15),  1 = Ep dst=b nb=a (rows 16-31),
//        self = rows 32-47,
//        2 = En dst=a nb=b (rows 48-63),  3 = En dst=b nb=a (rows 64-79).

#define ROW 128
#define SCAN_CHUNK 2048   // 256 threads x 8 logical elements

__global__ __launch_bounds__(256) void count_kernel(
    const int4* __restrict__ Ep2, const int4* __restrict__ En2,
    const int* __restrict__ Ep, const int* __restrict__ En,
    int* __restrict__ C, int Epairs, int Etail, int N, int S)
{
    int i = blockIdx.x * 256 + threadIdx.x;
    int stride = gridDim.x * 256;
    for (int e = i; e < Epairs; e += stride) {
        int4 p = Ep2[e];
        atomicAdd(&C[p.x * S],         1);
        atomicAdd(&C[(N + p.y) * S],   1);
        atomicAdd(&C[p.z * S],         1);
        atomicAdd(&C[(N + p.w) * S],   1);
        int4 q = En2[e];
        atomicAdd(&C[(2*N + q.x) * S], 1);
        atomicAdd(&C[(3*N + q.y) * S], 1);
        atomicAdd(&C[(2*N + q.z) * S], 1);
        atomicAdd(&C[(3*N + q.w) * S], 1);
    }
    if (i == 0 && Etail) {   // odd E tail edge
        int e = 2 * Epairs;
        atomicAdd(&C[Ep[2*e] * S],         1);
        atomicAdd(&C[(N + Ep[2*e+1]) * S], 1);
        atomicAdd(&C[(2*N + En[2*e]) * S],   1);
        atomicAdd(&C[(3*N + En[2*e+1]) * S], 1);
    }
}

__global__ __launch_bounds__(256) void scan1_kernel(
    const int* __restrict__ C, int* __restrict__ O, int* __restrict__ BS,
    int M, int S)
{
    __shared__ int sdata[256];
    const int tid = threadIdx.x;
    const int base = blockIdx.x * SCAN_CHUNK + tid * 8;
    int v[8]; int s = 0;
#pragma unroll
    for (int j = 0; j < 8; ++j) {
        int idx = base + j;
        v[j] = (idx < M) ? C[(size_t)idx * S] : 0;
        s += v[j];
    }
    sdata[tid] = s;
    __syncthreads();
#pragma unroll
    for (int off = 1; off < 256; off <<= 1) {
        int x = (tid >= off) ? sdata[tid - off] : 0;
        __syncthreads();
        sdata[tid] += x;
        __syncthreads();
    }
    if (tid == 255) BS[blockIdx.x] = sdata[255];
    int run = sdata[tid] - s;
#pragma unroll
    for (int j = 0; j < 8; ++j) {
        int idx = base + j;
        if (idx < M) O[(size_t)idx * S] = run;
        run += v[j];
    }
}

__global__ __launch_bounds__(256) void scan2_kernel(int* __restrict__ BS, int n)
{
    __shared__ int sdata[256];
    const int tid = threadIdx.x;
    int v = (tid < n) ? BS[tid] : 0;
    sdata[tid] = v;
    __syncthreads();
#pragma unroll
    for (int off = 1; off < 256; off <<= 1) {
        int x = (tid >= off) ? sdata[tid - off] : 0;
        __syncthreads();
        sdata[tid] += x;
        __syncthreads();
    }
    if (tid < n) BS[tid] = sdata[tid] - v;
}

__global__ __launch_bounds__(256) void scan3_kernel(
    int* __restrict__ O, const int* __restrict__ BS, int M, int S)
{
    const int add = BS[blockIdx.x];
    const int base = blockIdx.x * SCAN_CHUNK + threadIdx.x;
#pragma unroll
    for (int j = 0; j < 8; ++j) {
        int idx = base + j * 256;
        if (idx < M) O[(size_t)idx * S] += add;
    }
}

__global__ __launch_bounds__(256) void fill_kernel(
    const int4* __restrict__ Ep2, const int4* __restrict__ En2,
    const int* __restrict__ Ep, const int* __restrict__ En,
    int* __restrict__ O, int* __restrict__ idxbuf,
    int Epairs, int Etail, int N, int S)
{
    int i = blockIdx.x * 256 + threadIdx.x;
    int stride = gridDim.x * 256;
    for (int e = i; e < Epairs; e += stride) {
        int4 p = Ep2[e];
        idxbuf[atomicAdd(&O[p.x * S],         1)] = p.y;
        idxbuf[atomicAdd(&O[(N + p.y) * S],   1)] = p.x;
        idxbuf[atomicAdd(&O[p.z * S],         1)] = p.w;
        idxbuf[atomicAdd(&O[(N + p.w) * S],   1)] = p.z;
        int4 q = En2[e];
        idxbuf[atomicAdd(&O[(2*N + q.x) * S], 1)] = q.y;
        idxbuf[atomicAdd(&O[(3*N + q.y) * S], 1)] = q.x;
        idxbuf[atomicAdd(&O[(2*N + q.z) * S], 1)] = q.w;
        idxbuf[atomicAdd(&O[(3*N + q.w) * S], 1)] = q.z;
    }
    if (i == 0 && Etail) {
        int e = 2 * Epairs;
        int a = Ep[2*e], b = Ep[2*e+1];
        idxbuf[atomicAdd(&O[a * S],         1)] = b;
        idxbuf[atomicAdd(&O[(N + b) * S],   1)] = a;
        int c = En[2*e], d = En[2*e+1];
        idxbuf[atomicAdd(&O[(2*N + c) * S], 1)] = d;
        idxbuf[atomicAdd(&O[(3*N + d) * S], 1)] = c;
    }
}

// 256 threads per node: elem = tid&127 picks the (k,o) output element,
// h = tid>>7 picks which half of the 80-row W-column / neighbor list this
// thread covers. 40 weights per thread stay in registers.
__global__ __launch_bounds__(256, 4) void pull_kernel(
    const float* __restrict__ f_in,
    const int*   __restrict__ C,
    const int*   __restrict__ O,      // segment ENDs
    const int*   __restrict__ idxbuf,
    const float* __restrict__ W,      // (K, 80, 16)
    const float* __restrict__ bias,
    float*       __restrict__ out,
    int N, int S)
{
    __shared__ float sacc[2][5][ROW];
    __shared__ float syp[2][ROW];
    __shared__ float sa[ROW];

    const int tid  = threadIdx.x;
    const int elem = tid & 127;
    const int h    = tid >> 7;
    const int k    = elem >> 4;
    const int o    = elem & 15;

    float w[5][8];
#pragma unroll
    for (int s = 0; s < 5; ++s)
#pragma unroll
        for (int i = 0; i < 8; ++i)
            w[s][i] = W[k*1280 + (s*16 + h*8 + i)*16 + o];
    const float bb = bias[elem];

    for (int n = blockIdx.x; n < N; n += gridDim.x) {
#pragma unroll
        for (int l = 0; l < 4; ++l) {
            const int end = O[(size_t)(l*N + n) * S];
            const int beg = end - C[(size_t)(l*N + n) * S];
            float acc = 0.f;
            int j = beg + h;
            for (; j + 6 < end; j += 8) {       // 4 gathers in flight
                int j0 = idxbuf[j],   j1 = idxbuf[j+2];
                int j2 = idxbuf[j+4], j3 = idxbuf[j+6];
                float x0 = f_in[(size_t)j0*ROW + elem];
                float x1 = f_in[(size_t)j1*ROW + elem];
                float x2 = f_in[(size_t)j2*ROW + elem];
                float x3 = f_in[(size_t)j3*ROW + elem];
                acc += x0 + x1 + x2 + x3;
            }
            for (; j < end; j += 2)
                acc += f_in[(size_t)idxbuf[j]*ROW + elem];
            const int s = (l < 2) ? l : l + 1;  // slots 0,1,3,4
            sacc[h][s][elem] = acc;
        }
        sacc[h][2][elem] = h ? 0.f : f_in[(size_t)n*ROW + elem];
        __syncthreads();

        float y = 0.f;
#pragma unroll
        for (int s = 0; s < 5; ++s) {
            const float* m0 = &sacc[0][s][k*16 + h*8];
            const float* m1 = &sacc[1][s][k*16 + h*8];
#pragma unroll
            for (int i = 0; i < 8; ++i)
                y += (m0[i] + m1[i]) * w[s][i];
        }
        syp[h][elem] = y;
        __syncthreads();

        float a = 0.f;
        if (h == 0) {
            a = tanhf(syp[0][elem] + syp[1][elem] + bb);
            sa[elem] = a;
        }
        __syncthreads();
        if (h == 0) {
            float ss = 0.f;
#pragma unroll
            for (int k2 = 0; k2 < 8; ++k2) {
                float v = sa[k2*16 + o];
                ss += v * v;
            }
            out[(size_t)n*ROW + elem] = a / fmaxf(sqrtf(ss), 1e-12f);
        }
        __syncthreads();   // protect LDS before next node iteration
    }
}

extern "C" void kernel_launch(void* const* d_in, const int* in_sizes, int n_in,
                              void* d_out, int out_size, void* d_ws, size_t ws_size,
                              hipStream_t stream) {
    const float* f_in = (const float*)d_in[0];
    const int*   Ep   = (const int*)d_in[1];
    const int*   En   = (const int*)d_in[2];
    const float* W    = (const float*)d_in[3];
    const float* b    = (const float*)d_in[4];
    float* out = (float*)d_out;

    const int N = in_sizes[0] / ROW;
    const int E = in_sizes[1] / 2;
    const int Epairs = E / 2;
    const int Etail  = E & 1;
    const int M = 4 * N;                 // CSR segments
    const size_t nEntries = (size_t)4 * E;
    const int nChunks = (M + SCAN_CHUNK - 1) / SCAN_CHUNK;

    // Pick cursor stride S (ints): 1 counter per 64B line if ws allows.
    // Layout: BS[256] | C[M*S] | O[M*S] | idxbuf[4E]
    int S = 16;
    while (S > 1) {
        size_t need = (256 + 2 * (size_t)M * S + nEntries) * sizeof(int);
        if (need <= ws_size) break;
        S >>= 1;
    }

    int* BS     = (int*)d_ws;
    int* C      = BS + 256;
    int* O      = C + (size_t)M * S;
    int* idxbuf = O + (size_t)M * S;

    hipMemsetAsync(C, 0, (size_t)M * S * sizeof(int), stream);

    count_kernel<<<1024, 256, 0, stream>>>((const int4*)Ep, (const int4*)En,
                                           Ep, En, C, Epairs, Etail, N, S);
    scan1_kernel<<<nChunks, 256, 0, stream>>>(C, O, BS, M, S);
    scan2_kernel<<<1, 256, 0, stream>>>(BS, nChunks);
    scan3_kernel<<<nChunks, 256, 0, stream>>>(O, BS, M, S);
    fill_kernel<<<2048, 256, 0, stream>>>((const int4*)Ep, (const int4*)En,
                                          Ep, En, O, idxbuf, Epairs, Etail, N, S);

    pull_kernel<<<8192, 256, 0, stream>>>(f_in, C, O, idxbuf, W, b, out, N, S);
}

// Round 5
// 1457.105 us; speedup vs baseline: 1.0934x; 1.0934x over previous
//
#include <hip/hip_runtime.h>
#include <math.h>

// SDNConv: N nodes, K=8 factors, DK=16. ROW = 128 floats/node.
// R5: single-atomic-pass CSR build. cnt[] doubles as cursor (atomicAdd gives
// the slot), entries stored at seg*PAD + slot. No count kernel, no scan.
// Overflow (slot >= PAD, probability ~0 for Poisson(16) degrees with PAD>=40)
// goes to an overflow list; ovf_kernel pushes those through W into d_out,
// which pull_kernel adds as a pre-accumulator before tanh. Correct for any PAD.
// Lists/segments: seg = l*N + dst.
//   l=0: Ep dst=a nb=b (W rows 0-15),  l=1: Ep dst=b nb=a (rows 16-31),
//   self = rows 32-47,
//   l=2: En dst=a nb=b (rows 48-63),  l=3: En dst=b nb=a (rows 64-79).

#define ROW 128

__device__ __forceinline__ void push_entry(
    int* __restrict__ cnt, int* __restrict__ ovfCnt, int* __restrict__ ovf,
    int* __restrict__ idxbuf, int seg, int src, int PAD, int ovfCap)
{
    int slot = atomicAdd(&cnt[seg], 1);
    if (slot < PAD) {
        idxbuf[(size_t)seg * PAD + slot] = src;
    } else {
        int oi = atomicAdd(ovfCnt, 1);
        if (oi < ovfCap) { ovf[2*oi] = seg; ovf[2*oi+1] = src; }
    }
}

__global__ __launch_bounds__(256) void fill_kernel(
    const int4* __restrict__ Ep2, const int4* __restrict__ En2,
    const int* __restrict__ Ep, const int* __restrict__ En,
    int* __restrict__ cnt, int* __restrict__ ovfCnt, int* __restrict__ ovf,
    int* __restrict__ idxbuf, int Epairs, int Etail, int N, int PAD, int ovfCap)
{
    int i = blockIdx.x * 256 + threadIdx.x;
    int stride = gridDim.x * 256;
    for (int e = i; e < Epairs; e += stride) {
        int4 p = Ep2[e];
        push_entry(cnt, ovfCnt, ovf, idxbuf, p.x,       p.y, PAD, ovfCap);
        push_entry(cnt, ovfCnt, ovf, idxbuf, N + p.y,   p.x, PAD, ovfCap);
        push_entry(cnt, ovfCnt, ovf, idxbuf, p.z,       p.w, PAD, ovfCap);
        push_entry(cnt, ovfCnt, ovf, idxbuf, N + p.w,   p.z, PAD, ovfCap);
        int4 q = En2[e];
        push_entry(cnt, ovfCnt, ovf, idxbuf, 2*N + q.x, q.y, PAD, ovfCap);
        push_entry(cnt, ovfCnt, ovf, idxbuf, 3*N + q.y, q.x, PAD, ovfCap);
        push_entry(cnt, ovfCnt, ovf, idxbuf, 2*N + q.z, q.w, PAD, ovfCap);
        push_entry(cnt, ovfCnt, ovf, idxbuf, 3*N + q.w, q.z, PAD, ovfCap);
    }
    if (i == 0 && Etail) {   // odd-E tail edge
        int e = 2 * Epairs;
        int a = Ep[2*e], b = Ep[2*e+1];
        push_entry(cnt, ovfCnt, ovf, idxbuf, a,     b, PAD, ovfCap);
        push_entry(cnt, ovfCnt, ovf, idxbuf, N + b, a, PAD, ovfCap);
        int c = En[2*e], d = En[2*e+1];
        push_entry(cnt, ovfCnt, ovf, idxbuf, 2*N + c, d, PAD, ovfCap);
        push_entry(cnt, ovfCnt, ovf, idxbuf, 3*N + d, c, PAD, ovfCap);
    }
}

// Push overflow entries through their W section into d_out (pre-accumulator).
// Expected count: 0. Always dispatched (same work every call).
__global__ __launch_bounds__(256) void ovf_kernel(
    const float* __restrict__ f_in, const float* __restrict__ W,
    const int* __restrict__ ovfCnt, const int* __restrict__ ovf,
    float* __restrict__ out, int N, int ovfCap)
{
    const int t = threadIdx.x & 127;
    const int k = t >> 4;
    const int o = t & 15;
    int nOv = *ovfCnt;
    if (nOv > ovfCap) nOv = ovfCap;
    const int group  = blockIdx.x * 2 + (threadIdx.x >> 7);
    const int stride = gridDim.x * 2;
    for (int i = group; i < nOv; i += stride) {
        int seg = ovf[2*i], src = ovf[2*i+1];
        int l = seg / N;
        int dst = seg - l * N;
        int s = (l < 2) ? l : l + 1;
        float y = 0.f;
#pragma unroll
        for (int ii = 0; ii < 16; ++ii)
            y += f_in[(size_t)src*ROW + k*16 + ii] * W[k*1280 + (s*16 + ii)*16 + o];
        unsafeAtomicAdd(&out[(size_t)dst*ROW + t], y);
    }
}

// 256 threads per node: elem = tid&127 is the (k,o) output element, h = tid>>7
// halves the W rows and the neighbor list. 40 weights/thread in registers.
__global__ __launch_bounds__(256, 4) void pull_kernel(
    const float* __restrict__ f_in,
    const int*   __restrict__ cnt,
    const int*   __restrict__ idxbuf,
    const float* __restrict__ W,      // (K, 80, 16)
    const float* __restrict__ bias,
    float*       __restrict__ out,    // pre-accumulated overflow; final output
    int N, int PAD)
{
    __shared__ float sacc[2][5][ROW];
    __shared__ float syp[2][ROW];
    __shared__ float sa[ROW];

    const int tid  = threadIdx.x;
    const int elem = tid & 127;
    const int h    = tid >> 7;
    const int k    = elem >> 4;
    const int o    = elem & 15;

    float w[5][8];
#pragma unroll
    for (int s = 0; s < 5; ++s)
#pragma unroll
        for (int i = 0; i < 8; ++i)
            w[s][i] = W[k*1280 + (s*16 + h*8 + i)*16 + o];
    const float bb = bias[elem];

    for (int n = blockIdx.x; n < N; n += gridDim.x) {
        float pre = 0.f;
        if (h == 0) pre = out[(size_t)n*ROW + elem];   // overflow pre-accum

#pragma unroll
        for (int l = 0; l < 4; ++l) {
            int c = cnt[l*N + n];
            if (c > PAD) c = PAD;
            const size_t base = (size_t)(l*N + n) * PAD;
            float acc = 0.f;
            int j = h;
            for (; j + 6 < c; j += 8) {        // 4 gathers in flight
                int j0 = idxbuf[base + j],     j1 = idxbuf[base + j + 2];
                int j2 = idxbuf[base + j + 4], j3 = idxbuf[base + j + 6];
                float x0 = f_in[(size_t)j0*ROW + elem];
                float x1 = f_in[(size_t)j1*ROW + elem];
                float x2 = f_in[(size_t)j2*ROW + elem];
                float x3 = f_in[(size_t)j3*ROW + elem];
                acc += x0 + x1 + x2 + x3;
            }
            for (; j < c; j += 2)
                acc += f_in[(size_t)idxbuf[base + j]*ROW + elem];
            const int s = (l < 2) ? l : l + 1;  // slots 0,1,3,4
            sacc[h][s][elem] = acc;
        }
        sacc[h][2][elem] = h ? 0.f : f_in[(size_t)n*ROW + elem];
        __syncthreads();

        float y = 0.f;
#pragma unroll
        for (int s = 0; s < 5; ++s) {
            const float* m0 = &sacc[0][s][k*16 + h*8];
            const float* m1 = &sacc[1][s][k*16 + h*8];
#pragma unroll
            for (int i = 0; i < 8; ++i)
                y += (m0[i] + m1[i]) * w[s][i];
        }
        syp[h][elem] = y;
        __syncthreads();

        float a = 0.f;
        if (h == 0) {
            a = tanhf(syp[0][elem] + syp[1][elem] + bb + pre);
            sa[elem] = a;
        }
        __syncthreads();
        if (h == 0) {
            float ss = 0.f;
#pragma unroll
            for (int k2 = 0; k2 < 8; ++k2) {
                float v = sa[k2*16 + o];
                ss += v * v;
            }
            out[(size_t)n*ROW + elem] = a / fmaxf(sqrtf(ss), 1e-12f);
        }
        __syncthreads();   // protect LDS before next node iteration
    }
}

extern "C" void kernel_launch(void* const* d_in, const int* in_sizes, int n_in,
                              void* d_out, int out_size, void* d_ws, size_t ws_size,
                              hipStream_t stream) {
    const float* f_in = (const float*)d_in[0];
    const int*   Ep   = (const int*)d_in[1];
    const int*   En   = (const int*)d_in[2];
    const float* W    = (const float*)d_in[3];
    const float* b    = (const float*)d_in[4];
    float* out = (float*)d_out;

    const int N = in_sizes[0] / ROW;
    const int E = in_sizes[1] / 2;
    const int Epairs = E / 2;
    const int Etail  = E & 1;
    const int M = 4 * N;                 // CSR segments

    // Choose PAD (slots per segment) to fit ws. Poisson(16) degrees: PAD>=40
    // means ~zero overflow; overflow path keeps any PAD correct.
    int PAD = 72;
    size_t fixed;
    do {
        PAD -= 8;
        fixed = ((size_t)M + 64 + (size_t)M * PAD) * sizeof(int);
    } while (PAD > 8 && fixed + 512 * 1024 > ws_size);
    size_t left = (ws_size > fixed) ? (ws_size - fixed) : 8;
    size_t ovfCapSz = left / (2 * sizeof(int));
    int ovfCap = (int)(ovfCapSz > (size_t)(1 << 22) ? (1 << 22) : ovfCapSz);
    if (ovfCap < 1) ovfCap = 1;

    // Layout: cnt[M] | ovfCnt[64] | idxbuf[M*PAD] | ovf[2*ovfCap]
    int* cnt    = (int*)d_ws;
    int* ovfCnt = cnt + M;
    int* idxbuf = ovfCnt + 64;
    int* ovf    = idxbuf + (size_t)M * PAD;

    hipMemsetAsync(cnt, 0, ((size_t)M + 64) * sizeof(int), stream);
    hipMemsetAsync(out, 0, (size_t)out_size * sizeof(float), stream);

    fill_kernel<<<2048, 256, 0, stream>>>((const int4*)Ep, (const int4*)En,
                                          Ep, En, cnt, ovfCnt, ovf, idxbuf,
                                          Epairs, Etail, N, PAD, ovfCap);
    ovf_kernel<<<64, 256, 0, stream>>>(f_in, W, ovfCnt, ovf, out, N, ovfCap);
    pull_kernel<<<8192, 256, 0, stream>>>(f_in, cnt, idxbuf, W, b, out, N, PAD);
}

// Round 6
// 1187.510 us; speedup vs baseline: 1.3417x; 1.2270x over previous
//
#include <hip/hip_runtime.h>
#include <math.h>

// SDNConv: N nodes, K=8 factors, DK=16. ROW = 128 floats/node.
// R6: float4 gathers in pull. Segment layout node-major: seg = 4*dst + l.
//   l=0: Ep dst=a nb=b (W rows 0-15),  l=1: Ep dst=b nb=a (rows 16-31),
//   self = rows 32-47,
//   l=2: En dst=a nb=b (rows 48-63),  l=3: En dst=b nb=a (rows 64-79).
// Build: single-atomic-pass padded-slot CSR (R5), overflow -> ovf_kernel
// pre-accumulates into d_out, pull adds it before tanh.

#define ROW 128
#define ROW4 32

__device__ __forceinline__ void push_entry(
    int* __restrict__ cnt, int* __restrict__ ovfCnt, int* __restrict__ ovf,
    int* __restrict__ idxbuf, int seg, int src, int PAD, int ovfCap)
{
    int slot = atomicAdd(&cnt[seg], 1);
    if (slot < PAD) {
        idxbuf[(size_t)seg * PAD + slot] = src;
    } else {
        int oi = atomicAdd(ovfCnt, 1);
        if (oi < ovfCap) { ovf[2*oi] = seg; ovf[2*oi+1] = src; }
    }
}

__global__ __launch_bounds__(256) void fill_kernel(
    const int4* __restrict__ Ep2, const int4* __restrict__ En2,
    const int* __restrict__ Ep, const int* __restrict__ En,
    int* __restrict__ cnt, int* __restrict__ ovfCnt, int* __restrict__ ovf,
    int* __restrict__ idxbuf, int Epairs, int Etail, int N, int PAD, int ovfCap)
{
    int i = blockIdx.x * 256 + threadIdx.x;
    int stride = gridDim.x * 256;
    for (int e = i; e < Epairs; e += stride) {
        int4 p = Ep2[e];
        push_entry(cnt, ovfCnt, ovf, idxbuf, 4*p.x + 0, p.y, PAD, ovfCap);
        push_entry(cnt, ovfCnt, ovf, idxbuf, 4*p.y + 1, p.x, PAD, ovfCap);
        push_entry(cnt, ovfCnt, ovf, idxbuf, 4*p.z + 0, p.w, PAD, ovfCap);
        push_entry(cnt, ovfCnt, ovf, idxbuf, 4*p.w + 1, p.z, PAD, ovfCap);
        int4 q = En2[e];
        push_entry(cnt, ovfCnt, ovf, idxbuf, 4*q.x + 2, q.y, PAD, ovfCap);
        push_entry(cnt, ovfCnt, ovf, idxbuf, 4*q.y + 3, q.x, PAD, ovfCap);
        push_entry(cnt, ovfCnt, ovf, idxbuf, 4*q.z + 2, q.w, PAD, ovfCap);
        push_entry(cnt, ovfCnt, ovf, idxbuf, 4*q.w + 3, q.z, PAD, ovfCap);
    }
    if (i == 0 && Etail) {   // odd-E tail edge
        int e = 2 * Epairs;
        int a = Ep[2*e], b = Ep[2*e+1];
        push_entry(cnt, ovfCnt, ovf, idxbuf, 4*a + 0, b, PAD, ovfCap);
        push_entry(cnt, ovfCnt, ovf, idxbuf, 4*b + 1, a, PAD, ovfCap);
        int c = En[2*e], d = En[2*e+1];
        push_entry(cnt, ovfCnt, ovf, idxbuf, 4*c + 2, d, PAD, ovfCap);
        push_entry(cnt, ovfCnt, ovf, idxbuf, 4*d + 3, c, PAD, ovfCap);
    }
}

// Push overflow entries through their W section into d_out (pre-accumulator).
// Expected count: 0. Always dispatched (same work every call).
__global__ __launch_bounds__(256) void ovf_kernel(
    const float* __restrict__ f_in, const float* __restrict__ W,
    const int* __restrict__ ovfCnt, const int* __restrict__ ovf,
    float* __restrict__ out, int N, int ovfCap)
{
    const int t = threadIdx.x & 127;
    const int k = t >> 4;
    const int o = t & 15;
    int nOv = *ovfCnt;
    if (nOv > ovfCap) nOv = ovfCap;
    const int group  = blockIdx.x * 2 + (threadIdx.x >> 7);
    const int stride = gridDim.x * 2;
    for (int i = group; i < nOv; i += stride) {
        int seg = ovf[2*i], src = ovf[2*i+1];
        int l = seg & 3;
        int dst = seg >> 2;
        int s = (l < 2) ? l : l + 1;
        float y = 0.f;
#pragma unroll
        for (int ii = 0; ii < 16; ++ii)
            y += f_in[(size_t)src*ROW + k*16 + ii] * W[k*1280 + (s*16 + ii)*16 + o];
        unsafeAtomicAdd(&out[(size_t)dst*ROW + t], y);
    }
}

// 256 threads per node. Gather phase: oct = tid>>5 -> (list l = oct>>1,
// half hh = oct&1); e4 = tid&31 -> float4 lane of the 512B row. One
// dwordx4 instruction per 32-lane group loads a whole neighbor row.
// Matmul phase: elem = tid&127 = (k,o), h = tid>>7 halves the W rows
// (40 regs/thread); partials combined through LDS (R3-proven).
__global__ __launch_bounds__(256, 4) void pull_kernel(
    const float4* __restrict__ f_in4,
    const float*  __restrict__ f_in,
    const int*    __restrict__ cnt,
    const int*    __restrict__ idxbuf,
    const float*  __restrict__ W,      // (K, 80, 16)
    const float*  __restrict__ bias,
    float*        __restrict__ out,    // overflow pre-accum in; final out
    int N, int PAD)
{
    __shared__ float4 sacc4[2][5][ROW4];   // 5120 B
    __shared__ float  syp[2][ROW];         // 1024 B
    __shared__ float  sa[ROW];             //  512 B

    const int tid  = threadIdx.x;
    const int elem = tid & 127;
    const int h    = tid >> 7;
    const int k    = elem >> 4;
    const int o    = elem & 15;
    const int oct  = tid >> 5;
    const int l    = oct >> 1;
    const int hh   = oct & 1;
    const int e4   = tid & 31;
    const int slot = (l < 2) ? l : l + 1;   // lists -> slots 0,1,3,4

    float w[5][8];
#pragma unroll
    for (int s = 0; s < 5; ++s)
#pragma unroll
        for (int i = 0; i < 8; ++i)
            w[s][i] = W[k*1280 + (s*16 + h*8 + i)*16 + o];
    const float bb = bias[elem];

    for (int n = blockIdx.x; n < N; n += gridDim.x) {
        float pre = (h == 0) ? out[(size_t)n*ROW + elem] : 0.f;

        int c = cnt[4*n + l];
        if (c > PAD) c = PAD;
        const size_t base = (size_t)(4*n + l) * PAD;
        const int mid = (c + 1) >> 1;
        int j         = hh ? mid : 0;
        const int end = hh ? c   : mid;

        float4 acc = make_float4(0.f, 0.f, 0.f, 0.f);
        for (; j + 3 < end; j += 4) {       // 4 row-gathers in flight
            int j0 = idxbuf[base + j],     j1 = idxbuf[base + j + 1];
            int j2 = idxbuf[base + j + 2], j3 = idxbuf[base + j + 3];
            float4 r0 = f_in4[(size_t)j0*ROW4 + e4];
            float4 r1 = f_in4[(size_t)j1*ROW4 + e4];
            float4 r2 = f_in4[(size_t)j2*ROW4 + e4];
            float4 r3 = f_in4[(size_t)j3*ROW4 + e4];
            acc.x += r0.x + r1.x + r2.x + r3.x;
            acc.y += r0.y + r1.y + r2.y + r3.y;
            acc.z += r0.z + r1.z + r2.z + r3.z;
            acc.w += r0.w + r1.w + r2.w + r3.w;
        }
        for (; j < end; ++j) {
            float4 r = f_in4[(size_t)idxbuf[base + j]*ROW4 + e4];
            acc.x += r.x; acc.y += r.y; acc.z += r.z; acc.w += r.w;
        }
        sacc4[hh][slot][e4] = acc;
        if (oct == 0) sacc4[0][2][e4] = f_in4[(size_t)n*ROW4 + e4];  // self
        if (oct == 1) sacc4[1][2][e4] = make_float4(0.f, 0.f, 0.f, 0.f);
        __syncthreads();

        float y = 0.f;
#pragma unroll
        for (int s = 0; s < 5; ++s) {
            const float* m0 = (const float*)&sacc4[0][s][0] + k*16 + h*8;
            const float* m1 = (const float*)&sacc4[1][s][0] + k*16 + h*8;
#pragma unroll
            for (int i = 0; i < 8; ++i)
                y += (m0[i] + m1[i]) * w[s][i];
        }
        syp[h][elem] = y;
        __syncthreads();

        float a = 0.f;
        if (h == 0) {
            a = tanhf(syp[0][elem] + syp[1][elem] + bb + pre);
            sa[elem] = a;
        }
        __syncthreads();
        if (h == 0) {
            float ss = 0.f;
#pragma unroll
            for (int k2 = 0; k2 < 8; ++k2) {
                float v = sa[k2*16 + o];
                ss += v * v;
            }
            out[(size_t)n*ROW + elem] = a / fmaxf(sqrtf(ss), 1e-12f);
        }
        __syncthreads();   // protect LDS before next node iteration
    }
}

extern "C" void kernel_launch(void* const* d_in, const int* in_sizes, int n_in,
                              void* d_out, int out_size, void* d_ws, size_t ws_size,
                              hipStream_t stream) {
    const float* f_in = (const float*)d_in[0];
    const int*   Ep   = (const int*)d_in[1];
    const int*   En   = (const int*)d_in[2];
    const float* W    = (const float*)d_in[3];
    const float* b    = (const float*)d_in[4];
    float* out = (float*)d_out;

    const int N = in_sizes[0] / ROW;
    const int E = in_sizes[1] / 2;
    const int Epairs = E / 2;
    const int Etail  = E & 1;
    const int M = 4 * N;                 // CSR segments

    // Choose PAD (slots per segment) to fit ws. Poisson(16) degrees: PAD>=40
    // means ~zero overflow; overflow path keeps any PAD correct.
    int PAD = 72;
    size_t fixed;
    do {
        PAD -= 8;
        fixed = ((size_t)M + 64 + (size_t)M * PAD) * sizeof(int);
    } while (PAD > 8 && fixed + 512 * 1024 > ws_size);
    size_t left = (ws_size > fixed) ? (ws_size - fixed) : 8;
    size_t ovfCapSz = left / (2 * sizeof(int));
    int ovfCap = (int)(ovfCapSz > (size_t)(1 << 22) ? (1 << 22) : ovfCapSz);
    if (ovfCap < 1) ovfCap = 1;

    // Layout: cnt[M] | ovfCnt[64] | idxbuf[M*PAD] | ovf[2*ovfCap]
    int* cnt    = (int*)d_ws;
    int* ovfCnt = cnt + M;
    int* idxbuf = ovfCnt + 64;
    int* ovf    = idxbuf + (size_t)M * PAD;

    hipMemsetAsync(cnt, 0, ((size_t)M + 64) * sizeof(int), stream);
    hipMemsetAsync(out, 0, (size_t)out_size * sizeof(float), stream);

    fill_kernel<<<2048, 256, 0, stream>>>((const int4*)Ep, (const int4*)En,
                                          Ep, En, cnt, ovfCnt, ovf, idxbuf,
                                          Epairs, Etail, N, PAD, ovfCap);
    ovf_kernel<<<64, 256, 0, stream>>>(f_in, W, ovfCnt, ovf, out, N, ovfCap);
    pull_kernel<<<8192, 256, 0, stream>>>((const float4*)f_in, f_in, cnt,
                                          idxbuf, W, b, out, N, PAD);
}